// Round 5
// baseline (259.878 us; speedup 1.0000x reference)
//
#include <hip/hip_runtime.h>

#define NPTS 131072
#define NE 8
#define DIN 90
#define NH 256

typedef __attribute__((ext_vector_type(8))) short bf16x8;
typedef __attribute__((ext_vector_type(4))) float f32x4;
typedef __attribute__((ext_vector_type(2))) float f32x2;
typedef __attribute__((ext_vector_type(4))) unsigned int u32x4;
typedef __attribute__((ext_vector_type(2))) unsigned int u32x2;
typedef __attribute__((ext_vector_type(4), aligned(4))) float f32x4a;
typedef __attribute__((ext_vector_type(2), aligned(4))) float f32x2a;

// exact RNE scalar (prep only)
__device__ __forceinline__ unsigned short f2bf(float f) {
  unsigned int u = __float_as_uint(f);
  u += 0x7fffu + ((u >> 16) & 1u);
  return (unsigned short)(u >> 16);
}

#if defined(__has_builtin) && __has_builtin(__builtin_amdgcn_cvt_pk_bf16_f32)
typedef __attribute__((ext_vector_type(2))) __bf16 bf16x2;
__device__ __forceinline__ unsigned int pkbf(float f0, float f1) {
  bf16x2 r = __builtin_amdgcn_cvt_pk_bf16_f32(f0, f1);
  return __builtin_bit_cast(unsigned int, r);
}
#else
__device__ __forceinline__ unsigned int pkbf(float f0, float f1) {
  unsigned int u0 = __float_as_uint(f0) + 0x7fffu;
  unsigned int u1 = __float_as_uint(f1) + 0x7fffu;
  return __builtin_amdgcn_perm(u1, u0, 0x07060302u);
}
#endif

__device__ __forceinline__ bf16x8 cvt8(f32x4 a, f32x4 b) {
  u32x4 r;
  r[0] = pkbf(a[0], a[1]);
  r[1] = pkbf(a[2], a[3]);
  r[2] = pkbf(b[0], b[1]);
  r[3] = pkbf(b[2], b[3]);
  return __builtin_bit_cast(bf16x8, r);
}

// prep, coalesced reads / scattered 2B writes
#define PREP_T (184320 + 12288 + 8192 + 24576)
__global__ __launch_bounds__(256) void prep(const float* __restrict__ W1,
                                            const float* __restrict__ W2,
                                            unsigned short* __restrict__ W1T,
                                            unsigned short* __restrict__ W2T) {
  int tid = blockIdx.x * 256 + threadIdx.x;
  if (tid < 184320) {
    float v = W1[tid];
    int n = tid & 255, r = tid >> 8;      // r = e*90+kp
    int kp = r % 90, e = r / 90;
    W1T[(size_t)(e * NH + n) * 96 + kp] = f2bf(v);
    return;
  }
  tid -= 184320;
  if (tid < 12288) {
    int kp = 90 + tid % 6, q = tid / 6;
    int n = q & 255, e = q >> 8;
    W1T[(size_t)(e * NH + n) * 96 + kp] = 0;
    return;
  }
  tid -= 12288;
  if (tid < 8192) {
    float v = W2[tid];
    int o = tid & 3, k = (tid >> 2) & 255, e = tid >> 10;
    W2T[(size_t)(e * 16 + o) * NH + k] = f2bf(v);
    return;
  }
  tid -= 8192;
  if (tid < 24576) {
    int k = tid & 255, q = tid >> 8;
    int o = 4 + q % 12, e = q / 12;
    W2T[(size_t)(e * 16 + o) * NH + k] = 0;
  }
}

// __launch_bounds__(256,4): force total VGPR+AGPR <= 128 so 4 blocks/CU fit.
// acc is mf-sequential (16 AGPR) + facc 16; sH halved (chunk-parity dim removed).
__global__ __launch_bounds__(256, 4) void meganerf_main(
    const float* __restrict__ x, const float* __restrict__ cent,
    const float* __restrict__ b1, const float* __restrict__ b2,
    const unsigned short* __restrict__ W1T, const unsigned short* __restrict__ W2T,
    float* __restrict__ out) {
  __shared__ unsigned short sH[4 * 2048];  // 16384 B wave-private h (A-frag order, per-chunk reuse)
  __shared__ float sW[NE][64];             // 2048 B
  __shared__ float sB2[64][4];             // 1024 B
  __shared__ float sB1[NE * NH];           // 8192 B  -> total 27648 B

  const int t    = threadIdx.x;
  const int lane = t & 63;
  const int wid  = t >> 6;
  const int l15  = lane & 15;
  const int l4   = lane >> 4;
  const int row0 = blockIdx.x * 64;
  const int gbase = wid * 2048;

  // ---- stage b1 -> LDS (coalesced) ----
#pragma unroll
  for (int j = 0; j < 2; ++j)
    *(f32x4*)&sB1[t * 4 + j * 1024] = *(const f32x4a*)&b1[t * 4 + j * 1024];

  // ---- feat fragments (MFMA B operand B[k][n=row]), regs for all experts ----
  bf16x8 bfr[4][3];
#pragma unroll
  for (int nf = 0; nf < 4; ++nf) {
    const float* gr = x + (size_t)(row0 + 16 * nf + l15) * 93 + 3;
    f32x4 v0, v1;
    v0 = *(const f32x4a*)(gr + 8 * l4);
    v1 = *(const f32x4a*)(gr + 8 * l4 + 4);
    bfr[nf][0] = cvt8(v0, v1);
    v0 = *(const f32x4a*)(gr + 32 + 8 * l4);
    v1 = *(const f32x4a*)(gr + 36 + 8 * l4);
    bfr[nf][1] = cvt8(v0, v1);
    if (l4 < 3) {
      v0 = *(const f32x4a*)(gr + 64 + 8 * l4);
      v1 = *(const f32x4a*)(gr + 68 + 8 * l4);
    } else {
      f32x2 tl = *(const f32x2a*)(gr + 88);
      v0[0] = tl[0]; v0[1] = tl[1]; v0[2] = 0.f; v0[3] = 0.f;
      v1[0] = 0.f; v1[1] = 0.f; v1[2] = 0.f; v1[3] = 0.f;
    }
    bfr[nf][2] = cvt8(v0, v1);
  }

  // ---- per-point expert weights ----
  if (t < 64) {
    const float* gx = x + (size_t)(row0 + t) * 93;
    float px = gx[0], py = gx[1], pz = gx[2];
    float dist[NE], inv[NE];
    float mind = 3.4e38f;
#pragma unroll
    for (int e = 0; e < NE; ++e) {
      float dx = px - cent[e * 3 + 0];
      float dy = py - cent[e * 3 + 1];
      float dz = pz - cent[e * 3 + 2];
      float d2 = dx * dx + dy * dy + dz * dz;
      float d = sqrtf(fmaxf(d2, 0.f));
      dist[e] = d;
      inv[e] = 1.f / (d + 1e-8f);
      mind = fminf(mind, d);
    }
    float s = 0.f;
#pragma unroll
    for (int e = 0; e < NE; ++e) {
      if (dist[e] > 2.0f * mind) inv[e] = 0.f;
      s += inv[e];
    }
    float rs = 1.f / s;
    float bb[4] = {0.f, 0.f, 0.f, 0.f};
#pragma unroll
    for (int e = 0; e < NE; ++e) {
      float w = inv[e] * rs;
      sW[e][t] = w;
#pragma unroll
      for (int o = 0; o < 4; ++o) bb[o] += w * b2[e * 4 + o];
    }
#pragma unroll
    for (int o = 0; o < 4; ++o) sB2[t][o] = bb[o];
  }
  __syncthreads();   // covers sB1, sW, sB2

  // ---- pipelined (expert, chunk) loop ----
  bf16x8 w1buf[2][6];   // W1T frags, prefetched one chunk ahead
  bf16x8 bwbuf[2];      // W2T frag, prefetched one chunk ahead (ISSUED BEFORE w1
                        // prefetches so layer-2's vmcnt wait never drains them)
  float wv[4];

  auto loadW1 = [&](int idx, int buf) {
    const int e = idx >> 1, c = idx & 1;
    const unsigned short* p =
        W1T + (size_t)(e * NH + 128 * c + 32 * wid + l15) * 96 + 8 * l4;
#pragma unroll
    for (int mf = 0; mf < 2; ++mf)
#pragma unroll
      for (int ks = 0; ks < 3; ++ks)
        w1buf[buf][mf * 3 + ks] = *(const bf16x8*)(p + mf * (16 * 96) + 32 * ks);
  };
  auto loadBW = [&](int idx, int buf) {
    const int e = idx >> 1, c = idx & 1;
    bwbuf[buf] = *(const bf16x8*)(W2T + (size_t)(e * 16 + l15) * NH +
                                  128 * c + 32 * wid + 8 * l4);
  };

  loadBW(0, 0);
  loadW1(0, 0);

  f32x4 facc[4] = {{0.f, 0.f, 0.f, 0.f}, {0.f, 0.f, 0.f, 0.f},
                   {0.f, 0.f, 0.f, 0.f}, {0.f, 0.f, 0.f, 0.f}};

#pragma unroll 2
  for (int i = 0; i < 16; ++i) {
    const int e = i >> 1, c = i & 1, cur = i & 1, nxt = cur ^ 1;
    const int colbase = 128 * c + 32 * wid;

    // current-iter LDS operands (issue early; ~120cy latency)
    f32x4 b1v0 = *(const f32x4*)&sB1[e * NH + colbase + 4 * l4];
    f32x4 b1v1 = *(const f32x4*)&sB1[e * NH + colbase + 16 + 4 * l4];
    if (c == 0) {
#pragma unroll
      for (int nf = 0; nf < 4; ++nf) wv[nf] = sW[e][16 * nf + l15];
    }

    // next-iter VMEM prefetch: bw FIRST (vmcnt FIFO), then the 6 W1T frags
    const int ip = (i + 1) & 15;
    loadBW(ip, nxt);
    loadW1(ip, nxt);

    // ---- layer 1, mf-sequential (acc = 16 AGPR live) ----
#pragma unroll
    for (int mf = 0; mf < 2; ++mf) {
      const f32x4 b1v = (mf == 0) ? b1v0 : b1v1;
      f32x4 acc[4];
#pragma unroll
      for (int nf = 0; nf < 4; ++nf)
        acc[nf] = __builtin_amdgcn_mfma_f32_16x16x32_bf16(
            w1buf[cur][mf * 3 + 0], bfr[nf][0], b1v, 0, 0, 0);
#pragma unroll
      for (int ks = 1; ks < 3; ++ks)
#pragma unroll
        for (int nf = 0; nf < 4; ++nf)
          acc[nf] = __builtin_amdgcn_mfma_f32_16x16x32_bf16(
              w1buf[cur][mf * 3 + ks], bfr[nf][ks], acc[nf], 0, 0, 0);

      // epilogue: relu*w, pack, wave-private A-frag-order store
#pragma unroll
      for (int nf = 0; nf < 4; ++nf) {
        const float w = wv[nf];
        f32x4 a = acc[nf];
        f32x2 p0, p1;
        p0[0] = a[0]; p0[1] = a[1];
        p1[0] = a[2]; p1[1] = a[3];
        const f32x2 z = {0.f, 0.f};
        p0 = __builtin_elementwise_max(p0, z) * w;
        p1 = __builtin_elementwise_max(p1, z) * w;
        u32x2 pk;
        pk[0] = pkbf(p0[0], p0[1]);
        pk[1] = pkbf(p1[0], p1[1]);
        *(u32x2*)&sH[gbase + (nf * 64 + (l15 + 16 * (2 * mf + (l4 >> 1)))) * 8 +
                     4 * (l4 & 1)] = pk;
      }
    }

    // ---- layer 2 (wave-private; bwbuf[cur] was loaded LAST iter -> no vm drain) ----
#pragma unroll
    for (int rf = 0; rf < 4; ++rf) {
      bf16x8 ah = *(const bf16x8*)&sH[gbase + (rf * 64 + lane) * 8];
      facc[rf] = __builtin_amdgcn_mfma_f32_16x16x32_bf16(ah, bwbuf[cur], facc[rf], 0, 0, 0);
    }
  }

  // ---- cross-wave reduction (sOutP aliased onto sH: 4*64*4 f32 = 16 KB exactly) ----
  __syncthreads();
  float* sOutP = (float*)sH;
  if (l15 < 4) {
#pragma unroll
    for (int rf = 0; rf < 4; ++rf)
#pragma unroll
      for (int r = 0; r < 4; ++r)
        sOutP[(wid * 64 + 16 * rf + 4 * l4 + r) * 4 + l15] = facc[rf][r];
  }
  __syncthreads();
  {
    const int row = t >> 2, o = t & 3;
    float v = sB2[row][o] + sOutP[(0 * 64 + row) * 4 + o] + sOutP[(1 * 64 + row) * 4 + o] +
              sOutP[(2 * 64 + row) * 4 + o] + sOutP[(3 * 64 + row) * 4 + o];
    out[row0 * 4 + t] = v;
  }
}

extern "C" void kernel_launch(void* const* d_in, const int* in_sizes, int n_in,
                              void* d_out, int out_size, void* d_ws, size_t ws_size,
                              hipStream_t stream) {
  const float* x    = (const float*)d_in[0];
  const float* cent = (const float*)d_in[1];
  const float* W1   = (const float*)d_in[2];
  const float* b1   = (const float*)d_in[3];
  const float* W2   = (const float*)d_in[4];
  const float* b2   = (const float*)d_in[5];
  float* out = (float*)d_out;

  unsigned short* W1T = (unsigned short*)d_ws;   // 393216 B
  unsigned short* W2T = W1T + NE * NH * 96;      // 65536 B

  prep<<<(PREP_T + 255) / 256, 256, 0, stream>>>(W1, W2, W1T, W2T);
  meganerf_main<<<NPTS / 64, 256, 0, stream>>>(x, cent, b1, b2, W1T, W2T, out);
}

// Round 6
// 163.058 us; speedup vs baseline: 1.5938x; 1.5938x over previous
//
#include <hip/hip_runtime.h>

#define NPTS 131072
#define NE 8
#define DIN 90
#define NH 256

typedef __attribute__((ext_vector_type(8))) short bf16x8;
typedef __attribute__((ext_vector_type(4))) float f32x4;
typedef __attribute__((ext_vector_type(2))) float f32x2;
typedef __attribute__((ext_vector_type(4))) unsigned int u32x4;
typedef __attribute__((ext_vector_type(2))) unsigned int u32x2;
typedef __attribute__((ext_vector_type(4), aligned(4))) float f32x4a;
typedef __attribute__((ext_vector_type(2), aligned(4))) float f32x2a;

// exact RNE scalar (prep only)
__device__ __forceinline__ unsigned short f2bf(float f) {
  unsigned int u = __float_as_uint(f);
  u += 0x7fffu + ((u >> 16) & 1u);
  return (unsigned short)(u >> 16);
}

#if defined(__has_builtin) && __has_builtin(__builtin_amdgcn_cvt_pk_bf16_f32)
typedef __attribute__((ext_vector_type(2))) __bf16 bf16x2;
__device__ __forceinline__ unsigned int pkbf(float f0, float f1) {
  bf16x2 r = __builtin_amdgcn_cvt_pk_bf16_f32(f0, f1);
  return __builtin_bit_cast(unsigned int, r);
}
#else
__device__ __forceinline__ unsigned int pkbf(float f0, float f1) {
  unsigned int u0 = __float_as_uint(f0) + 0x7fffu;
  unsigned int u1 = __float_as_uint(f1) + 0x7fffu;
  return __builtin_amdgcn_perm(u1, u0, 0x07060302u);
}
#endif

__device__ __forceinline__ bf16x8 cvt8(f32x4 a, f32x4 b) {
  u32x4 r;
  r[0] = pkbf(a[0], a[1]);
  r[1] = pkbf(a[2], a[3]);
  r[2] = pkbf(b[0], b[1]);
  r[3] = pkbf(b[2], b[3]);
  return __builtin_bit_cast(bf16x8, r);
}

// prep, coalesced reads / scattered 2B writes
#define PREP_T (184320 + 12288 + 8192 + 24576)
__global__ __launch_bounds__(256) void prep(const float* __restrict__ W1,
                                            const float* __restrict__ W2,
                                            unsigned short* __restrict__ W1T,
                                            unsigned short* __restrict__ W2T) {
  int tid = blockIdx.x * 256 + threadIdx.x;
  if (tid < 184320) {
    float v = W1[tid];
    int n = tid & 255, r = tid >> 8;      // r = e*90+kp
    int kp = r % 90, e = r / 90;
    W1T[(size_t)(e * NH + n) * 96 + kp] = f2bf(v);
    return;
  }
  tid -= 184320;
  if (tid < 12288) {
    int kp = 90 + tid % 6, q = tid / 6;
    int n = q & 255, e = q >> 8;
    W1T[(size_t)(e * NH + n) * 96 + kp] = 0;
    return;
  }
  tid -= 12288;
  if (tid < 8192) {
    float v = W2[tid];
    int o = tid & 3, k = (tid >> 2) & 255, e = tid >> 10;
    W2T[(size_t)(e * 16 + o) * NH + k] = f2bf(v);
    return;
  }
  tid -= 8192;
  if (tid < 24576) {
    int k = tid & 255, q = tid >> 8;
    int o = 4 + q % 12, e = q / 12;
    W2T[(size_t)(e * 16 + o) * NH + k] = 0;
  }
}

// launch_bounds (256,3): cap 170 regs -> NO spills (R5's (256,4)=128-cap spilled:
// WRITE_SIZE 2->197MB). Residency comes from actual alloc (~116 incl AGPR ->
// 4 waves/SIMD) and LDS 27648B (-> 5 blocks/CU) => 4 blocks/CU achievable.
__global__ __launch_bounds__(256, 3) void meganerf_main(
    const float* __restrict__ x, const float* __restrict__ cent,
    const float* __restrict__ b1, const float* __restrict__ b2,
    const unsigned short* __restrict__ W1T, const unsigned short* __restrict__ W2T,
    float* __restrict__ out) {
  __shared__ unsigned short sH[4 * 2048];  // 16384 B wave-private h (A-frag order)
  __shared__ float sW[NE][64];             // 2048 B
  __shared__ float sB2[64][4];             // 1024 B
  __shared__ float sB1[NE * NH];           // 8192 B  -> total 27648 B

  const int t    = threadIdx.x;
  const int lane = t & 63;
  const int wid  = t >> 6;
  const int l15  = lane & 15;
  const int l4   = lane >> 4;
  const int row0 = blockIdx.x * 64;
  const int gbase = wid * 2048;

  // ---- stage b1 -> LDS (coalesced) ----
#pragma unroll
  for (int j = 0; j < 2; ++j)
    *(f32x4*)&sB1[t * 4 + j * 1024] = *(const f32x4a*)&b1[t * 4 + j * 1024];

  // ---- feat fragments (MFMA B operand B[k][n=row]), regs for all experts ----
  bf16x8 bfr[4][3];
#pragma unroll
  for (int nf = 0; nf < 4; ++nf) {
    const float* gr = x + (size_t)(row0 + 16 * nf + l15) * 93 + 3;
    f32x4 v0, v1;
    v0 = *(const f32x4a*)(gr + 8 * l4);
    v1 = *(const f32x4a*)(gr + 8 * l4 + 4);
    bfr[nf][0] = cvt8(v0, v1);
    v0 = *(const f32x4a*)(gr + 32 + 8 * l4);
    v1 = *(const f32x4a*)(gr + 36 + 8 * l4);
    bfr[nf][1] = cvt8(v0, v1);
    if (l4 < 3) {
      v0 = *(const f32x4a*)(gr + 64 + 8 * l4);
      v1 = *(const f32x4a*)(gr + 68 + 8 * l4);
    } else {
      f32x2 tl = *(const f32x2a*)(gr + 88);
      v0[0] = tl[0]; v0[1] = tl[1]; v0[2] = 0.f; v0[3] = 0.f;
      v1[0] = 0.f; v1[1] = 0.f; v1[2] = 0.f; v1[3] = 0.f;
    }
    bfr[nf][2] = cvt8(v0, v1);
  }

  // ---- per-point expert weights ----
  if (t < 64) {
    const float* gx = x + (size_t)(row0 + t) * 93;
    float px = gx[0], py = gx[1], pz = gx[2];
    float dist[NE], inv[NE];
    float mind = 3.4e38f;
#pragma unroll
    for (int e = 0; e < NE; ++e) {
      float dx = px - cent[e * 3 + 0];
      float dy = py - cent[e * 3 + 1];
      float dz = pz - cent[e * 3 + 2];
      float d2 = dx * dx + dy * dy + dz * dz;
      float d = sqrtf(fmaxf(d2, 0.f));
      dist[e] = d;
      inv[e] = 1.f / (d + 1e-8f);
      mind = fminf(mind, d);
    }
    float s = 0.f;
#pragma unroll
    for (int e = 0; e < NE; ++e) {
      if (dist[e] > 2.0f * mind) inv[e] = 0.f;
      s += inv[e];
    }
    float rs = 1.f / s;
    float bb[4] = {0.f, 0.f, 0.f, 0.f};
#pragma unroll
    for (int e = 0; e < NE; ++e) {
      float w = inv[e] * rs;
      sW[e][t] = w;
#pragma unroll
      for (int o = 0; o < 4; ++o) bb[o] += w * b2[e * 4 + o];
    }
#pragma unroll
    for (int o = 0; o < 4; ++o) sB2[t][o] = bb[o];
  }
  __syncthreads();   // covers sB1, sW, sB2

  // ---- pipelined (expert, chunk) loop ----
  bf16x8 w1buf[2][6];   // W1T frags, prefetched one chunk ahead
  bf16x8 bwbuf[2];      // W2T frag, prefetched ahead, issued BEFORE w1 group
  float wv[4];

  auto loadW1 = [&](int idx, int buf) {
    const int e = idx >> 1, c = idx & 1;
    const unsigned short* p =
        W1T + (size_t)(e * NH + 128 * c + 32 * wid + l15) * 96 + 8 * l4;
#pragma unroll
    for (int mf = 0; mf < 2; ++mf)
#pragma unroll
      for (int ks = 0; ks < 3; ++ks)
        w1buf[buf][mf * 3 + ks] = *(const bf16x8*)(p + mf * (16 * 96) + 32 * ks);
  };
  auto loadBW = [&](int idx, int buf) {
    const int e = idx >> 1, c = idx & 1;
    bwbuf[buf] = *(const bf16x8*)(W2T + (size_t)(e * 16 + l15) * NH +
                                  128 * c + 32 * wid + 8 * l4);
  };

  loadBW(0, 0);
  loadW1(0, 0);

  f32x4 facc[4] = {{0.f, 0.f, 0.f, 0.f}, {0.f, 0.f, 0.f, 0.f},
                   {0.f, 0.f, 0.f, 0.f}, {0.f, 0.f, 0.f, 0.f}};

#pragma unroll 2
  for (int i = 0; i < 16; ++i) {
    const int e = i >> 1, c = i & 1, cur = i & 1, nxt = cur ^ 1;
    const int colbase = 128 * c + 32 * wid;

    // current-iter LDS operands (issue early; ~120cy latency)
    f32x4 b1v0 = *(const f32x4*)&sB1[e * NH + colbase + 4 * l4];
    f32x4 b1v1 = *(const f32x4*)&sB1[e * NH + colbase + 16 + 4 * l4];
    if (c == 0) {
#pragma unroll
      for (int nf = 0; nf < 4; ++nf) wv[nf] = sW[e][16 * nf + l15];
    }

    // next-iter VMEM prefetch: bw FIRST (vmcnt FIFO), then the 6 W1T frags
    const int ip = (i + 1) & 15;
    loadBW(ip, nxt);
    loadW1(ip, nxt);

    // ---- layer 1, mf-sequential (16 AGPR live) ----
#pragma unroll
    for (int mf = 0; mf < 2; ++mf) {
      const f32x4 b1v = (mf == 0) ? b1v0 : b1v1;
      f32x4 acc[4];
#pragma unroll
      for (int nf = 0; nf < 4; ++nf)
        acc[nf] = __builtin_amdgcn_mfma_f32_16x16x32_bf16(
            w1buf[cur][mf * 3 + 0], bfr[nf][0], b1v, 0, 0, 0);
#pragma unroll
      for (int ks = 1; ks < 3; ++ks)
#pragma unroll
        for (int nf = 0; nf < 4; ++nf)
          acc[nf] = __builtin_amdgcn_mfma_f32_16x16x32_bf16(
              w1buf[cur][mf * 3 + ks], bfr[nf][ks], acc[nf], 0, 0, 0);

      // epilogue: relu*w, pack, wave-private A-frag-order store
#pragma unroll
      for (int nf = 0; nf < 4; ++nf) {
        const float w = wv[nf];
        f32x4 a = acc[nf];
        f32x2 p0, p1;
        p0[0] = a[0]; p0[1] = a[1];
        p1[0] = a[2]; p1[1] = a[3];
        const f32x2 z = {0.f, 0.f};
        p0 = __builtin_elementwise_max(p0, z) * w;
        p1 = __builtin_elementwise_max(p1, z) * w;
        u32x2 pk;
        pk[0] = pkbf(p0[0], p0[1]);
        pk[1] = pkbf(p1[0], p1[1]);
        *(u32x2*)&sH[gbase + (nf * 64 + (l15 + 16 * (2 * mf + (l4 >> 1)))) * 8 +
                     4 * (l4 & 1)] = pk;
      }
    }

    // ---- layer 2 (wave-private; bwbuf[cur] loaded LAST iter -> no vm drain) ----
#pragma unroll
    for (int rf = 0; rf < 4; ++rf) {
      bf16x8 ah = *(const bf16x8*)&sH[gbase + (rf * 64 + lane) * 8];
      facc[rf] = __builtin_amdgcn_mfma_f32_16x16x32_bf16(ah, bwbuf[cur], facc[rf], 0, 0, 0);
    }
  }

  // ---- cross-wave reduction (sOutP aliased onto sH: 4*64*4 f32 = 4 KB) ----
  __syncthreads();
  float* sOutP = (float*)sH;
  if (l15 < 4) {
#pragma unroll
    for (int rf = 0; rf < 4; ++rf)
#pragma unroll
      for (int r = 0; r < 4; ++r)
        sOutP[(wid * 64 + 16 * rf + 4 * l4 + r) * 4 + l15] = facc[rf][r];
  }
  __syncthreads();
  {
    const int row = t >> 2, o = t & 3;
    float v = sB2[row][o] + sOutP[(0 * 64 + row) * 4 + o] + sOutP[(1 * 64 + row) * 4 + o] +
              sOutP[(2 * 64 + row) * 4 + o] + sOutP[(3 * 64 + row) * 4 + o];
    out[row0 * 4 + t] = v;
  }
}

extern "C" void kernel_launch(void* const* d_in, const int* in_sizes, int n_in,
                              void* d_out, int out_size, void* d_ws, size_t ws_size,
                              hipStream_t stream) {
  const float* x    = (const float*)d_in[0];
  const float* cent = (const float*)d_in[1];
  const float* W1   = (const float*)d_in[2];
  const float* b1   = (const float*)d_in[3];
  const float* W2   = (const float*)d_in[4];
  const float* b2   = (const float*)d_in[5];
  float* out = (float*)d_out;

  unsigned short* W1T = (unsigned short*)d_ws;   // 393216 B
  unsigned short* W2T = W1T + NE * NH * 96;      // 65536 B

  prep<<<(PREP_T + 255) / 256, 256, 0, stream>>>(W1, W2, W1T, W2T);
  meganerf_main<<<NPTS / 64, 256, 0, stream>>>(x, cent, b1, b2, W1T, W2T, out);
}